// Round 9
// baseline (142.989 us; speedup 1.0000x reference)
//
#include <hip/hip_runtime.h>

#define BB 32
#define NN 256
#define NF 16

typedef _Float16 half4 __attribute__((ext_vector_type(4)));
typedef float f32x4 __attribute__((ext_vector_type(4)));

// ws layout (floats): x/h ping-pong only (su/sv now computed in-block)
#define X0_OFF 0
#define X1_OFF 32768
#define H0_OFF 65536
#define H1_OFF 196608

__device__ __forceinline__ float dot4(float4 a, float4 b, float acc) {
    acc = fmaf(a.x, b.x, acc); acc = fmaf(a.y, b.y, acc);
    acc = fmaf(a.z, b.z, acc); acc = fmaf(a.w, b.w, acc);
    return acc;
}

// 1024 blocks x 256 threads; 3 launches total (init folded into layer 0).
// Block = (batch b, node-octet oct); wave w owns dsts j0=8*oct+w, j1=8*oct+4+w
// sharing each tile's u4/xs4 (now LDS reads, not L2-latency global loads).
// su[n][16] computed IN-BLOCK from h (1 thread/node, 256 FMA) into a
// stride-20 LDS array (rows 80B: 16B-aligned for ds_read_b128; 2-way bank
// alias = free). Tile-loop math identical to validated R8 (absmax 0.5):
//   A-frag: We2[k=4g+i][outfeat=c]  B-frag: m1[src=16t+c][k=4g+i]
//   C-frag: m-hat[outfeat=4g+r][src=c]; self-edge masked in g only
//   (w-path self-term cancels exactly in Sw*xj - Swx).
__global__ __launch_bounds__(256)
void layer_kernel(const float* __restrict__ xs, const float* __restrict__ charges,
                  const float* __restrict__ W_in, const float* __restrict__ b_in,
                  const float* __restrict__ x_in, const float* __restrict__ h_in,
                  float* __restrict__ x_out, float* __restrict__ h_out,
                  const float* __restrict__ vs, const float* __restrict__ Wv_l,
                  const float* __restrict__ We1_l, const float* __restrict__ be1_l,
                  const float* __restrict__ We2_l, const float* __restrict__ be2_l,
                  const float* __restrict__ Wx_l, const float* __restrict__ Wh1_l,
                  const float* __restrict__ bh1_l,
                  int first_layer, int final_layer) {
    __shared__ __align__(16) float  su[NN * 20];     // 20 KB, stride-20 rows
    __shared__ __align__(16) float4 sx[NN];          // 4 KB
    __shared__ __align__(16) float  sWaT[256];       // WsrcT: [k][f]
    __shared__ __align__(16) float  sWbT[256];       // WdstT: [k][f]
    __shared__ float  sWh1s[512];
    __shared__ __align__(16) float  sh8[8][NF];      // h of block's 8 dsts
    __shared__ float  svd[8][NF];                    // v_j of block's 8 dsts
    __shared__ float  sg[8][NF];
    __shared__ float  sWin[NF], sbin[NF], sbe1[NF];

    const int tid  = threadIdx.x;
    const int b    = blockIdx.x >> 5;
    const int oct  = blockIdx.x & 31;
    const int n0l  = 8 * oct;
    const size_t n0 = (size_t)b * NN + n0l;
    const int w    = tid >> 6;
    const int lane = tid & 63;
    const int c    = lane & 15;
    const int g    = lane >> 4;

    // ---- stage 1: weights, x, dst-h ----
    {
        const int f = tid >> 4, k = tid & 15;
        sWaT[k * NF + f] = We1_l[tid];          // transpose on stage
        sWbT[k * NF + f] = We1_l[256 + tid];
    }
    sWh1s[tid]       = Wh1_l[tid];
    sWh1s[256 + tid] = Wh1_l[256 + tid];
    if (tid < NF) {
        sbe1[tid] = be1_l[tid];
        if (first_layer) { sWin[tid] = W_in[tid]; sbin[tid] = b_in[tid]; }
    }
    if (first_layer) {
        const size_t n = (size_t)b * NN + tid;
        sx[tid] = make_float4(xs[n * 3 + 0], xs[n * 3 + 1], xs[n * 3 + 2], 0.f);
        if (tid < 128) {
            const int jd = tid >> 4, f = tid & 15;
            sh8[jd][f] = fmaxf(fmaf(charges[n0 + jd], W_in[f], b_in[f]), 0.f);
        }
    } else {
        sx[tid] = ((const float4*)x_in)[(size_t)b * NN + tid];
        if (tid < 32) {
            const int jd = tid >> 2, q = tid & 3;
            *(float4*)&sh8[jd][4 * q] =
                ((const float4*)(h_in + (n0 + jd) * NF))[q];
        }
    }
    __syncthreads();

    // ---- stage 2: su (1 thread per node) and svd (128 threads) ----
    {
        float4 hq0, hq1, hq2, hq3;
        if (first_layer) {
            const float cc = charges[(size_t)b * NN + tid];
            hq0 = make_float4(fmaxf(fmaf(cc, sWin[0], sbin[0]), 0.f),
                              fmaxf(fmaf(cc, sWin[1], sbin[1]), 0.f),
                              fmaxf(fmaf(cc, sWin[2], sbin[2]), 0.f),
                              fmaxf(fmaf(cc, sWin[3], sbin[3]), 0.f));
            hq1 = make_float4(fmaxf(fmaf(cc, sWin[4], sbin[4]), 0.f),
                              fmaxf(fmaf(cc, sWin[5], sbin[5]), 0.f),
                              fmaxf(fmaf(cc, sWin[6], sbin[6]), 0.f),
                              fmaxf(fmaf(cc, sWin[7], sbin[7]), 0.f));
            hq2 = make_float4(fmaxf(fmaf(cc, sWin[8], sbin[8]), 0.f),
                              fmaxf(fmaf(cc, sWin[9], sbin[9]), 0.f),
                              fmaxf(fmaf(cc, sWin[10], sbin[10]), 0.f),
                              fmaxf(fmaf(cc, sWin[11], sbin[11]), 0.f));
            hq3 = make_float4(fmaxf(fmaf(cc, sWin[12], sbin[12]), 0.f),
                              fmaxf(fmaf(cc, sWin[13], sbin[13]), 0.f),
                              fmaxf(fmaf(cc, sWin[14], sbin[14]), 0.f),
                              fmaxf(fmaf(cc, sWin[15], sbin[15]), 0.f));
        } else {
            const float4* h4 = (const float4*)(h_in + ((size_t)b * NN + tid) * NF);
            hq0 = h4[0]; hq1 = h4[1]; hq2 = h4[2]; hq3 = h4[3];
        }
#pragma unroll
        for (int q = 0; q < 4; ++q) {
            float4 uq;
            {
                const float4* wt = (const float4*)&sWaT[(4 * q + 0) * NF];
                uq.x = dot4(hq3, wt[3], dot4(hq2, wt[2], dot4(hq1, wt[1], dot4(hq0, wt[0], 0.f))));
            }
            {
                const float4* wt = (const float4*)&sWaT[(4 * q + 1) * NF];
                uq.y = dot4(hq3, wt[3], dot4(hq2, wt[2], dot4(hq1, wt[1], dot4(hq0, wt[0], 0.f))));
            }
            {
                const float4* wt = (const float4*)&sWaT[(4 * q + 2) * NF];
                uq.z = dot4(hq3, wt[3], dot4(hq2, wt[2], dot4(hq1, wt[1], dot4(hq0, wt[0], 0.f))));
            }
            {
                const float4* wt = (const float4*)&sWaT[(4 * q + 3) * NF];
                uq.w = dot4(hq3, wt[3], dot4(hq2, wt[2], dot4(hq1, wt[1], dot4(hq0, wt[0], 0.f))));
            }
            *(float4*)&su[tid * 20 + 4 * q] = uq;
        }
    }
    if (tid < 128) {
        const int jd = tid >> 4, k = tid & 15;
        const float4* hj = (const float4*)&sh8[jd][0];
        const float4* wt = (const float4*)&sWbT[k * NF];
        float v = sbe1[k];
        v = dot4(hj[0], wt[0], v);
        v = dot4(hj[1], wt[1], v);
        v = dot4(hj[2], wt[2], v);
        v = dot4(hj[3], wt[3], v);
        svd[jd][k] = v;
    }
    // afrag (global, independent of LDS) — issue before the barrier
    half4 afrag;
    afrag.x = (_Float16)We2_l[(4 * g + 0) * NF + c];
    afrag.y = (_Float16)We2_l[(4 * g + 1) * NF + c];
    afrag.z = (_Float16)We2_l[(4 * g + 2) * NF + c];
    afrag.w = (_Float16)We2_l[(4 * g + 3) * NF + c];
    const float4 wr4  = *(const float4*)(We1_l + 512 + 4 * g);
    const float4 be2f = *(const float4*)(be2_l + 4 * g);
    const float4 wxf  = *(const float4*)(Wx_l + 4 * g);
    __syncthreads();

    // ---- per-wave dst invariants ----
    const int j0 = n0l + w, j1 = n0l + 4 + w;
    const float4 xj0 = sx[j0];
    const float4 xj1 = sx[j1];
    const float4 v40 = *(const float4*)&svd[w][4 * g];
    const float4 v41 = *(const float4*)&svd[w + 4][4 * g];

    float Sw0 = 0.f, Swx0 = 0.f, Swy0 = 0.f, Swz0 = 0.f;
    float Sw1 = 0.f, Swx1 = 0.f, Swy1 = 0.f, Swz1 = 0.f;
    float g00 = 0.f, g01 = 0.f, g02 = 0.f, g03 = 0.f;
    float g10 = 0.f, g11 = 0.f, g12 = 0.f, g13 = 0.f;

#pragma unroll 2
    for (int t = 0; t < 16; ++t) {
        const int s = 16 * t + c;
        const float4 u4  = *(const float4*)&su[s * 20 + 4 * g];
        const float4 xs4 = sx[s];
        const f32x4 zc = {0.f, 0.f, 0.f, 0.f};
        // ---- dst 0 ----
        {
            const float dx = xj0.x - xs4.x, dy = xj0.y - xs4.y, dz = xj0.z - xs4.z;
            const float r2 = fmaf(dx, dx, fmaf(dy, dy, dz * dz));
            const float m0 = fmaxf(fmaf(r2, wr4.x, u4.x + v40.x), 0.f);
            const float m1 = fmaxf(fmaf(r2, wr4.y, u4.y + v40.y), 0.f);
            const float m2 = fmaxf(fmaf(r2, wr4.z, u4.z + v40.z), 0.f);
            const float m3 = fmaxf(fmaf(r2, wr4.w, u4.w + v40.w), 0.f);
            half4 bfrag;
            bfrag.x = (_Float16)m0; bfrag.y = (_Float16)m1;
            bfrag.z = (_Float16)m2; bfrag.w = (_Float16)m3;
            const f32x4 acc = __builtin_amdgcn_mfma_f32_16x16x16f16(afrag, bfrag, zc, 0, 0, 0);
            const float e0 = fmaxf(acc.x + be2f.x, 0.f);
            const float e1 = fmaxf(acc.y + be2f.y, 0.f);
            const float e2 = fmaxf(acc.z + be2f.z, 0.f);
            const float e3 = fmaxf(acc.w + be2f.w, 0.f);
            float wp = e0 * wxf.x;
            wp = fmaf(e1, wxf.y, wp);
            wp = fmaf(e2, wxf.z, wp);
            wp = fmaf(e3, wxf.w, wp);
            const float gsel = (s != j0) ? 1.f : 0.f;
            g00 = fmaf(e0, gsel, g00);
            g01 = fmaf(e1, gsel, g01);
            g02 = fmaf(e2, gsel, g02);
            g03 = fmaf(e3, gsel, g03);
            Sw0 += wp;
            Swx0 = fmaf(wp, xs4.x, Swx0);
            Swy0 = fmaf(wp, xs4.y, Swy0);
            Swz0 = fmaf(wp, xs4.z, Swz0);
        }
        // ---- dst 1 (reuses u4/xs4) ----
        {
            const float dx = xj1.x - xs4.x, dy = xj1.y - xs4.y, dz = xj1.z - xs4.z;
            const float r2 = fmaf(dx, dx, fmaf(dy, dy, dz * dz));
            const float m0 = fmaxf(fmaf(r2, wr4.x, u4.x + v41.x), 0.f);
            const float m1 = fmaxf(fmaf(r2, wr4.y, u4.y + v41.y), 0.f);
            const float m2 = fmaxf(fmaf(r2, wr4.z, u4.z + v41.z), 0.f);
            const float m3 = fmaxf(fmaf(r2, wr4.w, u4.w + v41.w), 0.f);
            half4 bfrag;
            bfrag.x = (_Float16)m0; bfrag.y = (_Float16)m1;
            bfrag.z = (_Float16)m2; bfrag.w = (_Float16)m3;
            const f32x4 acc = __builtin_amdgcn_mfma_f32_16x16x16f16(afrag, bfrag, zc, 0, 0, 0);
            const float e0 = fmaxf(acc.x + be2f.x, 0.f);
            const float e1 = fmaxf(acc.y + be2f.y, 0.f);
            const float e2 = fmaxf(acc.z + be2f.z, 0.f);
            const float e3 = fmaxf(acc.w + be2f.w, 0.f);
            float wp = e0 * wxf.x;
            wp = fmaf(e1, wxf.y, wp);
            wp = fmaf(e2, wxf.z, wp);
            wp = fmaf(e3, wxf.w, wp);
            const float gsel = (s != j1) ? 1.f : 0.f;
            g10 = fmaf(e0, gsel, g10);
            g11 = fmaf(e1, gsel, g11);
            g12 = fmaf(e2, gsel, g12);
            g13 = fmaf(e3, gsel, g13);
            Sw1 += wp;
            Swx1 = fmaf(wp, xs4.x, Swx1);
            Swy1 = fmaf(wp, xs4.y, Swy1);
            Swz1 = fmaf(wp, xs4.z, Swz1);
        }
    }

    // ---- out-of-loop reductions ----
#pragma unroll
    for (int off = 1; off < 64; off <<= 1) {
        Sw0  += __shfl_xor(Sw0,  off, 64);  Sw1  += __shfl_xor(Sw1,  off, 64);
        Swx0 += __shfl_xor(Swx0, off, 64);  Swx1 += __shfl_xor(Swx1, off, 64);
        Swy0 += __shfl_xor(Swy0, off, 64);  Swy1 += __shfl_xor(Swy1, off, 64);
        Swz0 += __shfl_xor(Swz0, off, 64);  Swz1 += __shfl_xor(Swz1, off, 64);
    }
#pragma unroll
    for (int off = 1; off < 16; off <<= 1) {
        g00 += __shfl_xor(g00, off, 64);  g10 += __shfl_xor(g10, off, 64);
        g01 += __shfl_xor(g01, off, 64);  g11 += __shfl_xor(g11, off, 64);
        g02 += __shfl_xor(g02, off, 64);  g12 += __shfl_xor(g12, off, 64);
        g03 += __shfl_xor(g03, off, 64);  g13 += __shfl_xor(g13, off, 64);
    }
    if ((lane & 15) == 0) {
        *(float4*)&sg[w][4 * g]     = make_float4(g00, g01, g02, g03);
        *(float4*)&sg[w + 4][4 * g] = make_float4(g10, g11, g12, g13);
    }
    __syncthreads();

    // ---- node epilogue: lanes 0..15 -> j0 (slot w); 32..47 -> j1 (slot w+4) ----
    const int is0 = (lane < 16);
    const int is1 = (lane >= 32 && lane < 48);
    if (is0 || is1) {
        const int f = lane & 15;
        const int slot = is0 ? w : (w + 4);
        const int jm   = is0 ? j0 : j1;
        const float SwS = is0 ? Sw0  : Sw1;
        const float SxS = is0 ? Swx0 : Swx1;
        const float SyS = is0 ? Swy0 : Swy1;
        const float SzS = is0 ? Swz0 : Swz1;
        const float4 xjm = is0 ? xj0 : xj1;
        const size_t nj = (size_t)b * NN + jm;
        float hd = bh1_l[f];
        float hv = 0.f;
#pragma unroll
        for (int k = 0; k < NF; ++k) {
            const float hjk = sh8[slot][k];
            hd = fmaf(hjk, sWh1s[k * NF + f], hd);
            hv = fmaf(hjk, Wv_l[k], hv);
        }
#pragma unroll
        for (int k = 0; k < NF; ++k) {
            hd = fmaf(sg[slot][k], sWh1s[(NF + k) * NF + f], hd);
        }
        const float hnew = sh8[slot][f] + fmaxf(hd, 0.f);
        if (!final_layer) h_out[nj * NF + f] = hnew;
        if (f < 3) {
            const float xc = (f == 0) ? xjm.x : ((f == 1) ? xjm.y : xjm.z);
            const float Sc = (f == 0) ? SxS  : ((f == 1) ? SyS  : SzS);
            const float agg = (SwS * xc - Sc) * (1.f / 255.f);
            const float xnew = xc + agg + vs[nj * 3 + f] * hv;
            if (final_layer) x_out[nj * 3 + f] = xnew;
            else             x_out[nj * 4 + f] = xnew;
        }
        if (!final_layer && f == 3) x_out[nj * 4 + 3] = 0.f;
    }
}

extern "C" void kernel_launch(void* const* d_in, const int* in_sizes, int n_in,
                              void* d_out, int out_size, void* d_ws, size_t ws_size,
                              hipStream_t stream) {
    const float* xs      = (const float*)d_in[0];
    const float* vs      = (const float*)d_in[1];
    const float* charges = (const float*)d_in[2];
    const float* W_in    = (const float*)d_in[3];
    const float* b_in    = (const float*)d_in[4];
    const float* W_v     = (const float*)d_in[5];
    const float* We1     = (const float*)d_in[6];
    const float* be1     = (const float*)d_in[7];
    const float* We2     = (const float*)d_in[8];
    const float* be2     = (const float*)d_in[9];
    const float* Wx      = (const float*)d_in[10];
    const float* Wh1     = (const float*)d_in[11];
    const float* bh1     = (const float*)d_in[12];
    // d_in[13]=src, d_in[14]=dst: fully-connected pattern, computed analytically.

    float* ws = (float*)d_ws;
    float* x0 = ws + X0_OFF;
    float* x1 = ws + X1_OFF;
    float* h0 = ws + H0_OFF;
    float* h1 = ws + H1_OFF;
    float* out = (float*)d_out;

    // layer 0 (init folded in): inputs xs/charges -> x1,h1
    hipLaunchKernelGGL(layer_kernel, dim3(1024), dim3(256), 0, stream,
                       xs, charges, W_in, b_in, x0, h0, x1, h1,
                       vs, W_v + 0 * 16, We1 + 0 * 528, be1 + 0 * 16, We2 + 0 * 256,
                       be2 + 0 * 16, Wx + 0 * 16, Wh1 + 0 * 512, bh1 + 0 * 16, 1, 0);
    // layer 1: x1,h1 -> x0,h0
    hipLaunchKernelGGL(layer_kernel, dim3(1024), dim3(256), 0, stream,
                       xs, charges, W_in, b_in, x1, h1, x0, h0,
                       vs, W_v + 1 * 16, We1 + 1 * 528, be1 + 1 * 16, We2 + 1 * 256,
                       be2 + 1 * 16, Wx + 1 * 16, Wh1 + 1 * 512, bh1 + 1 * 16, 0, 0);
    // layer 2 (final): x0,h0 -> out
    hipLaunchKernelGGL(layer_kernel, dim3(1024), dim3(256), 0, stream,
                       xs, charges, W_in, b_in, x0, h0, out, h1,
                       vs, W_v + 2 * 16, We1 + 2 * 528, be1 + 2 * 16, We2 + 2 * 256,
                       be2 + 2 * 16, Wx + 2 * 16, Wh1 + 2 * 512, bh1 + 2 * 16, 0, 1);
}